// Round 3
// baseline (268.594 us; speedup 1.0000x reference)
//
#include <hip/hip_runtime.h>
#include <math.h>

// Problem constants
#define BB 8
#define NN 2048
#define FIN 256
#define FMSG 128
#define TOPK 32
#define NODES (BB * NN)   // 16384

typedef __attribute__((ext_vector_type(8))) short short8;   // 8 bf16 (4 VGPRs)
typedef __attribute__((ext_vector_type(4))) float f32x4;

// fp32x8 -> bf16x8, round-to-nearest-even (inputs are finite randoms, no NaN)
__device__ inline short8 cvt8(const float4 a, const float4 b) {
  float f[8] = {a.x, a.y, a.z, a.w, b.x, b.y, b.z, b.w};
  short8 r;
#pragma unroll
  for (int i = 0; i < 8; ++i) {
    unsigned u = __float_as_uint(f[i]);
    u += 0x7FFFu + ((u >> 16) & 1u);
    r[i] = (short)(u >> 16);
  }
  return r;
}

// ---------------- Kernel 1: Xm = X @ W^T + b  via bf16 MFMA ----------------
// Block = 256 threads (4 waves). Each block: 16 node-rows; wave w owns cols
// [32w, 32w+32). Per wave: 2 accumulators of 16x16, K-loop of 8 x (K=32).
// A-frag: row = lane&15, k = kg*8+e (8 contiguous k). B-frag: col = lane&15,
// same k packing (B = W^T, so lane reads W[col][k0..k0+8) contiguous).
// D: col = lane&15, row = (lane>>4)*4 + reg.
__global__ __launch_bounds__(256) void linear_mfma(
    const float* __restrict__ X, const float* __restrict__ W,
    const float* __restrict__ bias, float* __restrict__ Xm) {
  const int lane = threadIdx.x & 63;
  const int w = threadIdx.x >> 6;
  const int l15 = lane & 15;
  const int kg = lane >> 4;          // k-group 0..3
  const int nb = blockIdx.x * 16;    // node-row base
  const int colbase = w * 32;

  const float* xp  = X + (long long)(nb + l15) * FIN + kg * 8;
  const float* wp0 = W + (long long)(colbase + l15) * FIN + kg * 8;
  const float* wp1 = wp0 + 16 * FIN;

  f32x4 acc0 = {0.f, 0.f, 0.f, 0.f};
  f32x4 acc1 = {0.f, 0.f, 0.f, 0.f};

#pragma unroll
  for (int kk = 0; kk < FIN; kk += 32) {
    float4 xa = *reinterpret_cast<const float4*>(xp + kk);
    float4 xb = *reinterpret_cast<const float4*>(xp + kk + 4);
    float4 wa = *reinterpret_cast<const float4*>(wp0 + kk);
    float4 wb = *reinterpret_cast<const float4*>(wp0 + kk + 4);
    float4 wc = *reinterpret_cast<const float4*>(wp1 + kk);
    float4 wd = *reinterpret_cast<const float4*>(wp1 + kk + 4);
    short8 af = cvt8(xa, xb);
    short8 b0 = cvt8(wa, wb);
    short8 b1 = cvt8(wc, wd);
    acc0 = __builtin_amdgcn_mfma_f32_16x16x32_bf16(af, b0, acc0, 0, 0, 0);
    acc1 = __builtin_amdgcn_mfma_f32_16x16x32_bf16(af, b1, acc1, 0, 0, 0);
  }

  const float bv0 = bias[colbase + l15];
  const float bv1 = bias[colbase + 16 + l15];
#pragma unroll
  for (int r = 0; r < 4; ++r) {
    const int row = nb + kg * 4 + r;
    Xm[(long long)row * FMSG + colbase + l15]      = acc0[r] + bv0;
    Xm[(long long)row * FMSG + colbase + 16 + l15] = acc1[r] + bv1;
  }
}

// ------------- Kernel 2: fused top-K + BN/LeakyReLU weighted aggregate -------------
// One wave per node; block = 4 waves; grid = NODES/4.
// batch = blockIdx.x & 7 -> one batch's 1 MB Xm slice stays hot per XCD L2.
// Lane r-th element maps to column j = (r>>2)*256 + lane*4 + (r&3)  (coalesced:
// each float4 load covers 1 KB contiguous across the wave).
__global__ __launch_bounds__(256) void topk_agg_kernel(
    const float* __restrict__ A, const float* __restrict__ Xm,
    const float* __restrict__ gamma, const float* __restrict__ beta,
    const float* __restrict__ mean, const float* __restrict__ var,
    float* __restrict__ out) {
  __shared__ unsigned long long cand[4][64];

  const int lane = threadIdx.x & 63;
  const int w = threadIdx.x >> 6;
  const int batch = blockIdx.x & 7;
  const int n = ((blockIdx.x >> 3) << 2) + w;          // node within batch
  const long long row = (long long)batch * NN + n;

  // ---- coalesced load of my 32 elements of the adjacency row ----
  const float* arow = A + row * NN;
  float a[32];
#pragma unroll
  for (int q = 0; q < 8; ++q) {
    float4 v = *reinterpret_cast<const float4*>(arow + q * 256 + lane * 4);
    a[q * 4 + 0] = v.x; a[q * 4 + 1] = v.y; a[q * 4 + 2] = v.z; a[q * 4 + 3] = v.w;
  }
  // column index of element r:  jg = ((r>>2)<<8) | (lane<<2) | (r&3)

  // ---- per-lane max ----
  float lmax = a[0];
#pragma unroll
  for (int r = 1; r < 32; ++r) lmax = fmaxf(lmax, a[r]);

  // ---- T = 32nd largest lane-max (descending bitonic over 64 lane maxima) ----
  float sv = lmax;
#pragma unroll
  for (int kk = 2; kk <= 64; kk <<= 1) {
#pragma unroll
    for (int jj = kk >> 1; jj > 0; jj >>= 1) {
      float o = __shfl_xor(sv, jj);
      bool takeMax = ((lane & kk) == 0) ^ ((lane & jj) != 0);
      sv = takeMax ? fmaxf(sv, o) : fminf(sv, o);
    }
  }
  const float T = __shfl(sv, 31);   // >=32 elements are >= T, guaranteed

  // ---- count candidates and exclusive prefix across lanes ----
  int cnt = 0;
#pragma unroll
  for (int r = 0; r < 32; ++r) cnt += (a[r] >= T) ? 1 : 0;
  int pre = cnt;
#pragma unroll
  for (int jj = 1; jj < 64; jj <<= 1) {
    int o = __shfl_up(pre, jj);
    if (lane >= jj) pre += o;
  }
  const int C = __shfl(pre, 63);
  int off = pre - cnt;

  float selv = 0.0f;     // lanes 0..31 hold the top-32 values, descending
  int selj = 0;

  if (C <= 64) {
    // ---- fast path: compact candidates to LDS, bitonic-sort 64b keys ----
    unsigned long long* cb = cand[w];
    cb[lane] = 0ULL;
    __builtin_amdgcn_wave_barrier();
#pragma unroll
    for (int r = 0; r < 32; ++r) {
      if (a[r] >= T) {
        unsigned fb = __float_as_uint(a[r]);
        int jg = ((r >> 2) << 8) | (lane << 2) | (r & 3);
        unsigned long long kk = ((unsigned long long)fb << 32) |
                                (unsigned)(NN - 1 - jg);   // value desc, idx asc
        cb[off] = kk;
        ++off;
      }
    }
    __builtin_amdgcn_wave_barrier();
    unsigned long long key = cb[lane];
#pragma unroll
    for (int kk = 2; kk <= 64; kk <<= 1) {
#pragma unroll
      for (int jj = kk >> 1; jj > 0; jj >>= 1) {
        unsigned long long o = __shfl_xor(key, jj);
        bool takeMax = ((lane & kk) == 0) ^ ((lane & jj) != 0);
        key = (takeMax == (key >= o)) ? key : o;
      }
    }
    if (lane < TOPK) {
      selv = __uint_as_float((unsigned)(key >> 32));
      selj = (NN - 1) - (int)(key & 0xFFFFFFFFull);
    }
  } else {
    // ---- rare exact fallback: iterative argmax with removal mask ----
    float bmax = a[0]; int bidx = 0;
#pragma unroll
    for (int r = 1; r < 32; ++r) {
      if (a[r] > bmax) { bmax = a[r]; bidx = r; }
    }
    unsigned rm = 0u;
    for (int t = 0; t < TOPK; ++t) {
      float bv = bmax;
      int bj = ((bidx >> 2) << 8) | (lane << 2) | (bidx & 3);
#pragma unroll
      for (int s = 1; s < 64; s <<= 1) {
        float ov = __shfl_xor(bv, s);
        int oj = __shfl_xor(bj, s);
        if (ov > bv || (ov == bv && oj < bj)) { bv = ov; bj = oj; }
      }
      if (lane == t) { selv = bv; selj = bj; }
      if (((bj >> 2) & 63) == lane) {     // I own the winner: remove it
        rm |= 1u << (((bj >> 8) << 2) | (bj & 3));
        bmax = -3.402823466e+38f; bidx = 0;
#pragma unroll
        for (int r = 0; r < 32; ++r) {
          float av = ((rm >> r) & 1u) ? -3.402823466e+38f : a[r];
          if (av > bmax) { bmax = av; bidx = r; }
        }
      }
    }
  }

  // ---- sum of selected values (lanes >= 32 contribute 0) ----
  float vs = selv;
#pragma unroll
  for (int jj = 1; jj < 64; jj <<= 1) vs += __shfl_xor(vs, jj);
  const float recip = 1.0f / (vs + 1e-12f);

  // ---- aggregation: each lane owns 2 channels ----
  const int c0 = lane * 2;
  const float2 gm = *reinterpret_cast<const float2*>(gamma + c0);
  const float2 bt = *reinterpret_cast<const float2*>(beta + c0);
  const float2 mn = *reinterpret_cast<const float2*>(mean + c0);
  const float2 vr = *reinterpret_cast<const float2*>(var + c0);
  const float sc0 = gm.x / sqrtf(vr.x + 1e-5f);
  const float sc1 = gm.y / sqrtf(vr.y + 1e-5f);
  const float sh0 = bt.x - mn.x * sc0;
  const float sh1 = bt.y - mn.y * sc1;

  const float* xmb = Xm + (long long)batch * NN * FMSG;
  const float2 xs = *reinterpret_cast<const float2*>(xmb + (long long)n * FMSG + c0);

  float acc0 = 0.0f, acc1 = 0.0f;
#pragma unroll
  for (int t = 0; t < TOPK; ++t) {
    float wgt = __shfl(selv, t) * recip;
    int j = __shfl(selj, t);
    float2 xn = *reinterpret_cast<const float2*>(xmb + (long long)j * FMSG + c0);
    float p0 = xs.x + xn.x;
    float p1 = xs.y + xn.y;
    float h0 = p0 * sc0 + sh0;
    float h1 = p1 * sc1 + sh1;
    h0 = fmaxf(h0, 0.01f * h0);
    h1 = fmaxf(h1, 0.01f * h1);
    acc0 += wgt * h0;
    acc1 += wgt * h1;
  }
  *reinterpret_cast<float2*>(out + row * FMSG + c0) = make_float2(acc0, acc1);
}

// ---------------------------------------------------------------------------
extern "C" void kernel_launch(void* const* d_in, const int* in_sizes, int n_in,
                              void* d_out, int out_size, void* d_ws, size_t ws_size,
                              hipStream_t stream) {
  const float* X     = (const float*)d_in[0];
  const float* A     = (const float*)d_in[1];
  const float* W     = (const float*)d_in[2];
  const float* bias  = (const float*)d_in[3];
  const float* gamma = (const float*)d_in[4];
  const float* beta  = (const float*)d_in[5];
  const float* mean  = (const float*)d_in[6];
  const float* var   = (const float*)d_in[7];
  float* out = (float*)d_out;
  float* Xm  = (float*)d_ws;   // 16384 * 128 floats = 8 MB

  linear_mfma<<<NODES / 16, 256, 0, stream>>>(X, W, bias, Xm);
  topk_agg_kernel<<<NODES / 4, 256, 0, stream>>>(A, Xm, gamma, beta, mean, var, out);
}